// Round 1
// baseline (206.602 us; speedup 1.0000x reference)
//
#include <hip/hip_runtime.h>

// skipConnection: out[i] = in[i,0]*w + in[i,1]*(1-w)
// Memory-bound elementwise. 192 MiB total traffic -> ~32 us HBM floor,
// BUT the whole working set fits in the 256 MiB Infinity Cache, so in a
// steady-state bench loop plain cacheable accesses can run out of L3.
// Change vs prev: removed __builtin_nontemporal_* (nt = evict-first,
// which forcibly defeats L3 residency for an L3-fitting working set).

typedef float v4f __attribute__((ext_vector_type(4)));

__global__ __launch_bounds__(256) void skipConnection_kernel(
    const v4f* __restrict__ in,   // [N/2] v4f = [N] (x,y) pairs packed 2-per-vec
    const float* __restrict__ wp, // device scalar weight
    v4f* __restrict__ out,        // [N/4] v4f outputs
    int n4)                       // N/4
{
    int i = blockIdx.x * blockDim.x + threadIdx.x;
    if (i >= n4) return;

    const float w  = wp[0];
    const float wm = 1.0f - w;

    // lane reads 32 contiguous bytes: pairs (4i..4i+3). Cacheable -> L3 keeps
    // the 192 MiB working set resident across bench iterations.
    v4f a = in[2 * i];     // (x0,y0,x1,y1)
    v4f b = in[2 * i + 1]; // (x2,y2,x3,y3)

    v4f o;
    o.x = fmaf(a.x, w, a.y * wm);
    o.y = fmaf(a.z, w, a.w * wm);
    o.z = fmaf(b.x, w, b.y * wm);
    o.w = fmaf(b.z, w, b.w * wm);

    out[i] = o;
}

extern "C" void kernel_launch(void* const* d_in, const int* in_sizes, int n_in,
                              void* d_out, int out_size, void* d_ws, size_t ws_size,
                              hipStream_t stream) {
    const float* in = (const float*)d_in[0];   // [N,2] fp32
    const float* wp = (const float*)d_in[1];   // [1,1] fp32
    float* out      = (float*)d_out;           // [N,1] fp32

    int n  = out_size;        // N = 16777216
    int n4 = n / 4;           // N divisible by 4
    int block = 256;
    int grid  = (n4 + block - 1) / block;

    skipConnection_kernel<<<grid, block, 0, stream>>>(
        (const v4f*)in, wp, (v4f*)out, n4);
}

// Round 2
// 204.089 us; speedup vs baseline: 1.0123x; 1.0123x over previous
//
#include <hip/hip_runtime.h>

// skipConnection: out[i] = in[i,0]*w + in[i,1]*(1-w)
// Memory-bound elementwise. 192 MiB mandatory traffic -> ~30 us kernel floor.
// Bench total (~200 us) includes ~160 us of harness re-poison fills (2x 512 MiB
// at ~80 us, seen in rocprof) which also thrash L3 every iteration -> no
// cross-iteration cache reuse is possible. Therefore:
//  - nontemporal load/store: stream never reused, skip cache allocation
//  - capped persistent grid (2048 blocks x 256), grid-stride, unroll 2
//    (G11 launch shape for memory-bound ops; long-lived blocks, no tail)

typedef float v4f __attribute__((ext_vector_type(4)));

__global__ __launch_bounds__(256) void skipConnection_kernel(
    const v4f* __restrict__ in,   // [N/2] v4f = [N] (x,y) pairs packed 2-per-vec
    const float* __restrict__ wp, // device scalar weight
    v4f* __restrict__ out,        // [N/4] v4f outputs
    int n4)                       // N/4
{
    const float w  = wp[0];
    const float wm = 1.0f - w;

    const int stride = gridDim.x * blockDim.x;
    #pragma unroll 2
    for (int i = blockIdx.x * blockDim.x + threadIdx.x; i < n4; i += stride) {
        // lane reads 32 contiguous bytes: pairs (4i..4i+3). Streaming, zero reuse.
        v4f a = __builtin_nontemporal_load(&in[2 * i]);     // (x0,y0,x1,y1)
        v4f b = __builtin_nontemporal_load(&in[2 * i + 1]); // (x2,y2,x3,y3)

        v4f o;
        o.x = fmaf(a.x, w, a.y * wm);
        o.y = fmaf(a.z, w, a.w * wm);
        o.z = fmaf(b.x, w, b.y * wm);
        o.w = fmaf(b.z, w, b.w * wm);

        __builtin_nontemporal_store(o, &out[i]);
    }
}

extern "C" void kernel_launch(void* const* d_in, const int* in_sizes, int n_in,
                              void* d_out, int out_size, void* d_ws, size_t ws_size,
                              hipStream_t stream) {
    const float* in = (const float*)d_in[0];   // [N,2] fp32
    const float* wp = (const float*)d_in[1];   // [1,1] fp32
    float* out      = (float*)d_out;           // [N,1] fp32

    int n  = out_size;        // N = 16777216
    int n4 = n / 4;           // N divisible by 4
    int block = 256;
    // capped persistent grid: 2048 blocks (8/CU), grid-stride covers the rest
    int grid  = (n4 + block - 1) / block;
    if (grid > 2048) grid = 2048;

    skipConnection_kernel<<<grid, block, 0, stream>>>(
        (const v4f*)in, wp, (v4f*)out, n4);
}